// Round 5
// baseline (149.103 us; speedup 1.0000x reference)
//
#include <hip/hip_runtime.h>
#include <hip/hip_bf16.h>

#define QUERY_DIM 128
#define HIDDEN 128

typedef float f32x4 __attribute__((ext_vector_type(4)));

__device__ __forceinline__ float dot4(f32x4 a, f32x4 b) {
    return a.x * b.x + a.y * b.y + a.z * b.z + a.w * b.w;
}

// ---------------------------------------------------------------------------
// Kernel 1 (combo): blocks 0..63  -> W[e][d] = sum_h WQ[h][e]*WK[h][d]
//                   blocks 64..   -> segment starts via binary search
// ---------------------------------------------------------------------------
__global__ __launch_bounds__(256) void combo_kernel(const float* __restrict__ WQ,
                                                    const float* __restrict__ WK,
                                                    float* __restrict__ W,
                                                    const int* __restrict__ idx,
                                                    int* __restrict__ start,
                                                    int nmols, int total) {
    int b = blockIdx.x;
    int t = threadIdx.x;
    if (b < 64) {
        int e = b * 2 + (t >> 7);   // 0..127
        int d = t & 127;
        float acc = 0.f;
#pragma unroll 8
        for (int h = 0; h < HIDDEN; ++h) {
            acc += WQ[h * QUERY_DIM + e] * WK[h * 128 + d];
        }
        W[e * 128 + d] = acc;
    } else {
        int m = (b - 64) * 256 + t;
        if (m > nmols) return;
        if (m == nmols) { start[m] = total; return; }
        int lo = 0, hi = total;
        while (lo < hi) {
            int mid = (lo + hi) >> 1;
            if (idx[mid] < m) lo = mid + 1; else hi = mid;
        }
        start[m] = lo;
    }
}

// ---------------------------------------------------------------------------
// Kernel 2: R = query @ W    [nmols,128]. 16 rows/block, 256 threads.
// ---------------------------------------------------------------------------
__global__ __launch_bounds__(256) void qproj_kernel(const float* __restrict__ Q,
                                                    const float* __restrict__ W,
                                                    float* __restrict__ R, int nmols) {
    __shared__ float wl[64 * 128];  // 32 KB (half of W)
    __shared__ float ql[16 * 128];  // 8 KB (16 query rows)
    int t = threadIdx.x;
    int c = t & 127;
    int g = t >> 7;
    long row0 = (long)blockIdx.x * 16;

    for (int i = t * 4; i < 16 * 128; i += 256 * 4) {
        *(float4*)&ql[i] = *(const float4*)&Q[row0 * QUERY_DIM + i];
    }

    float acc[8] = {0.f, 0.f, 0.f, 0.f, 0.f, 0.f, 0.f, 0.f};

    for (int half = 0; half < 2; ++half) {
        __syncthreads();
        for (int i = t * 4; i < 64 * 128; i += 256 * 4) {
            *(float4*)&wl[i] = *(const float4*)&W[half * 64 * 128 + i];
        }
        __syncthreads();
        for (int d = 0; d < 64; ++d) {
            float wv = wl[d * 128 + c];
            int dg = half * 64 + d;
#pragma unroll
            for (int r = 0; r < 8; ++r) {
                acc[r] += ql[(g * 8 + r) * 128 + dg] * wv;
            }
        }
    }
#pragma unroll
    for (int r = 0; r < 8; ++r) {
        long row = row0 + g * 8 + r;
        if (row < nmols) R[row * 128 + c] = acc[r];
    }
}

// ---------------------------------------------------------------------------
// Kernel 3 (fused, dominant): per segment — scores + stable softmax.
// One wave per segment. 8 lanes per key (64B/lane), 8 keys per iteration:
//   - 4 independent dwordx4 loads/lane (lane-monotone addresses, 64B stride;
//     j=0 pulls the 4KB block, j=1..3 L1-hot)
//   - depth-3 butterfly (xor 4,2,1) reduces all 8 keys at once
//   - running max is per-lane; single 6-level reduce at segment end
// Tail lanes clamp to row s1-1 (valid address) and are masked from max/store.
// ---------------------------------------------------------------------------
__global__ __launch_bounds__(256) void fused_kernel(const float* __restrict__ K,
                                                    const float* __restrict__ R,
                                                    const int* __restrict__ start,
                                                    float* __restrict__ weights,
                                                    float* scores,   // no restrict: store+load alias
                                                    int nmols) {
    const int lane = threadIdx.x & 63;
    const int sub  = lane & 7;       // 64B-chunk slot within the key row
    const int grp  = lane >> 3;      // key slot 0..7 within the iteration
    const int wave = (blockIdx.x * 256 + threadIdx.x) >> 6;
    const int nwaves = gridDim.x * 4;
    const float sc = 0.08838834764831845f;  // 1/sqrt(128)

    for (int s = wave; s < nmols; s += nwaves) {
        int s0 = start[s], s1 = start[s + 1];
        if (s0 >= s1) continue;

        // R chunk for this lane: floats [sub*16, sub*16+16)
        const f32x4* rp = (const f32x4*)(R + (long)s * 128) + sub * 4;
        f32x4 r0 = rp[0], r1 = rp[1], r2 = rp[2], r3 = rp[3];

        // ---- phase 1: scores + per-lane running max ----
        float mx = -__builtin_inff();
        for (int k0 = s0; k0 < s1; k0 += 8) {
            int kk = k0 + grp;
            int kc = kk < s1 ? kk : s1 - 1;          // clamp to valid row
            const f32x4* kp = (const f32x4*)(K + (long)kc * 128) + sub * 4;
            f32x4 a0 = kp[0];
            f32x4 a1 = kp[1];
            f32x4 a2 = kp[2];
            f32x4 a3 = kp[3];
            float v = dot4(a0, r0) + dot4(a1, r1) + dot4(a2, r2) + dot4(a3, r3);
            v += __shfl_xor(v, 4, 64);
            v += __shfl_xor(v, 2, 64);
            v += __shfl_xor(v, 1, 64);               // all 8 lanes of grp hold key's dot
            v *= sc;
            if (kk < s1) {
                if (sub == 0) scores[kk] = v;        // 8 lanes -> 32B contiguous
                mx = fmaxf(mx, v);
            }
        }
#pragma unroll
        for (int off = 32; off > 0; off >>= 1) mx = fmaxf(mx, __shfl_xor(mx, off, 64));

        // make the scores stores visible before re-reading
        asm volatile("s_waitcnt vmcnt(0)" ::: "memory");

        // ---- phase 2: sum of exp (scores L1/L2-hot) ----
        float sum = 0.f;
        for (int i = s0 + lane; i < s1; i += 64) sum += __expf(scores[i] - mx);
#pragma unroll
        for (int off = 32; off > 0; off >>= 1) sum += __shfl_xor(sum, off, 64);
        float inv = 1.0f / sum;

        // ---- phase 3: weights ----
        for (int i = s0 + lane; i < s1; i += 64)
            weights[i] = __expf(scores[i] - mx) * inv;
    }
}

// ---------------------------------------------------------------------------
extern "C" void kernel_launch(void* const* d_in, const int* in_sizes, int n_in,
                              void* d_out, int out_size, void* d_ws, size_t ws_size,
                              hipStream_t stream) {
    const float* Q   = (const float*)d_in[0];
    const float* K   = (const float*)d_in[1];
    const float* WQ  = (const float*)d_in[2];
    const float* WK  = (const float*)d_in[3];
    const int*   idx = (const int*)d_in[4];

    const int nmols = in_sizes[0] / QUERY_DIM;   // 16384
    const int total = in_sizes[4];               // 1048576

    float* weights = (float*)d_out;              // output 0
    float* scores  = (float*)d_out + total;      // output 1

    char* ws = (char*)d_ws;
    float* W        = (float*)ws;                        // 64 KB
    int*   segstart = (int*)(ws + 65536);                // (nmols+1)*4
    float* R        = (float*)(ws + 65536 + 131072);     // nmols*128*4 = 8 MB

    int segblocks = (nmols + 1 + 255) / 256;
    combo_kernel<<<64 + segblocks, 256, 0, stream>>>(WQ, WK, W, idx, segstart, nmols, total);
    qproj_kernel<<<(nmols + 15) / 16, 256, 0, stream>>>(Q, W, R, nmols);
    fused_kernel<<<2048, 256, 0, stream>>>(K, R, segstart, weights, scores, nmols);
}